// Round 11
// baseline (84.102 us; speedup 1.0000x reference)
//
#include <hip/hip_runtime.h>
#include <math.h>

// Problem constants (fixed by the reference's setup_inputs)
constexpr int B = 2, G = 8, D = 16, H = 256, W = 320;
constexpr int HW = H * W;
constexpr float EPS = 1e-5f;

typedef _Float16 half8  __attribute__((ext_vector_type(8)));
typedef _Float16 h2v    __attribute__((ext_vector_type(2)));
typedef float    f32x16 __attribute__((ext_vector_type(16)));

union H8U { half8 h; unsigned u[4]; uint4 u4; };
union H2U { h2v h; unsigned u; };

// wbuf layout:
//   u32  [0..256)    aL1  : 64 lanes x 4 dwords (L1 A-frag, P rows 0-15, S rows 16-31, K>=8 zero)
//   u32  [256..512)  aL2P : 64 lanes x 4 dwords (W1P, K-PERMUTED to C-layout order)
//   u32  [512..768)  aL2S : 64 lanes x 4 dwords (W1S, K-permuted)
//   f32  [768..784)  b0P[16]; [784..792) b1P[8]; [792..800) w2P[8]
//   f32  [800] bias2P; [801] bias2S
//   f32  [804..820)  b0S[16]; [820..828) b1S[8]; [828..836) w2S[8]
constexpr int WB_TOTAL = 840;

__device__ __forceinline__ float sigmoidf_(float x) {
    return 1.0f / (1.0f + __expf(-x));
}
__device__ __forceinline__ int reflect_(int i, int n) {
    return i < 0 ? -i : (i >= n ? 2 * n - 2 - i : i);
}
__device__ __forceinline__ unsigned pack2_(float a, float b) {
    H2U p; p.h.x = (_Float16)a; p.h.y = (_Float16)b; return p.u;
}

// ---------------------------------------------------------------------------
// k_prep: MFMA-ready fragments (BN folded) + bias tables.
// A-frag (32x32x16): lane l holds A[row=l&31][k=(l>>5)*8+e], e=0..7.
// aL2*: K-permuted so slot k=(l>>5)*8+e maps to l1-row (e&3)+8*(e>>2)+((l>>5)?4:0)
// -> L2 B-fragment becomes "each lane packs its own acc regs" (no shuffles).
// ---------------------------------------------------------------------------
__global__ __launch_bounds__(320) void k_prep(
    const float* __restrict__ sw0, const float* __restrict__ sg0, const float* __restrict__ sb0,
    const float* __restrict__ sw1, const float* __restrict__ sg1, const float* __restrict__ sb1,
    const float* __restrict__ sw2, const float* __restrict__ sbias2,
    const float* __restrict__ pw0, const float* __restrict__ pg0, const float* __restrict__ pb0,
    const float* __restrict__ pw1, const float* __restrict__ pg1, const float* __restrict__ pb1,
    const float* __restrict__ pw2, const float* __restrict__ pbias2,
    float* __restrict__ wbuf)
{
    const int t = threadIdx.x;
    const float rs = rsqrtf(1.0f + EPS);
    unsigned* wu = (unsigned*)wbuf;

    if (t < 64) {
        // aL1: rows 0-15 = W0P, rows 16-31 = W0S; K columns 8..15 = 0
        unsigned dw[4] = {0u, 0u, 0u, 0u};
        if (t < 32) {
            const int row = t;
            #pragma unroll
            for (int j = 0; j < 4; ++j) {
                float a0, a1;
                if (row < 16) {
                    const float s = pg0[row] * rs;
                    a0 = pw0[row * 8 + 2 * j] * s; a1 = pw0[row * 8 + 2 * j + 1] * s;
                } else {
                    const float s = sg0[row - 16] * rs;
                    a0 = sw0[(row - 16) * 8 + 2 * j] * s; a1 = sw0[(row - 16) * 8 + 2 * j + 1] * s;
                }
                dw[j] = pack2_(a0, a1);
            }
        }
        #pragma unroll
        for (int j = 0; j < 4; ++j) wu[t * 4 + j] = dw[j];
    } else if (t < 128) {
        // aL2P, K-permuted
        const int l = t - 64, row = l & 31;
        const int e4 = (l >> 5) ? 4 : 0;
        unsigned dw[4] = {0u, 0u, 0u, 0u};
        if (row < 8) {
            const float s = pg1[row] * rs;
            #pragma unroll
            for (int j = 0; j < 4; ++j) {
                const int e0 = 2 * j, e1 = 2 * j + 1;
                const int k0 = (e0 & 3) + 8 * (e0 >> 2) + e4;
                const int k1 = (e1 & 3) + 8 * (e1 >> 2) + e4;
                dw[j] = pack2_(pw1[row * 16 + k0] * s, pw1[row * 16 + k1] * s);
            }
        }
        #pragma unroll
        for (int j = 0; j < 4; ++j) wu[256 + l * 4 + j] = dw[j];
    } else if (t < 192) {
        // aL2S, K-permuted
        const int l = t - 128, row = l & 31;
        const int e4 = (l >> 5) ? 4 : 0;
        unsigned dw[4] = {0u, 0u, 0u, 0u};
        if (row < 8) {
            const float s = sg1[row] * rs;
            #pragma unroll
            for (int j = 0; j < 4; ++j) {
                const int e0 = 2 * j, e1 = 2 * j + 1;
                const int k0 = (e0 & 3) + 8 * (e0 >> 2) + e4;
                const int k1 = (e1 & 3) + 8 * (e1 >> 2) + e4;
                dw[j] = pack2_(sw1[row * 16 + k0] * s, sw1[row * 16 + k1] * s);
            }
        }
        #pragma unroll
        for (int j = 0; j < 4; ++j) wu[512 + l * 4 + j] = dw[j];
    } else {
        const int u = t - 192;
        if (u < 16)       wbuf[768 + u] = pb0[u];
        else if (u < 24)  wbuf[784 + (u - 16)] = pb1[u - 16];
        else if (u < 32)  wbuf[792 + (u - 24)] = pw2[u - 24];
        else if (u == 32) wbuf[800] = pbias2[0];
        else if (u == 33) wbuf[801] = sbias2[0];
        else if (u < 50)  wbuf[804 + (u - 34)] = sb0[u - 34];
        else if (u < 58)  wbuf[820 + (u - 50)] = sb1[u - 50];
        else if (u < 66)  wbuf[828 + (u - 58)] = sw2[u - 58];
    }
}

// ---------------------------------------------------------------------------
// k_fused (MFMA, shuffle-free): block = 256 thr (4 waves) = 64 px x 16 dt.
// Wave w: 8 groups (g8) of 32 items = (dt = 4w+(g8>>1), px half (g8&1)).
// L1 MFMA computes biased/relu'd l1P (regs 0-7) AND raw preS (regs 8-15,
// stashed; vw applied later by linearity). K-permuted aL2 makes the L2
// B-fragment = pack of the lane's own registers. L3 = 4 FMA + 1 shfl.
// ---------------------------------------------------------------------------
__global__ __launch_bounds__(256, 4) void k_fused(
    const float* __restrict__ x1,
    const float* __restrict__ depth_sample,
    const float* __restrict__ depth_min, const float* __restrict__ depth_max,
    const float* __restrict__ wbuf,
    float* __restrict__ s_out, float* __restrict__ xn_out)
{
    __shared__ float h3buf[16][64];
    __shared__ float vwbuf[64];
    __shared__ float sbuf[16][64];

    const int tid = threadIdx.x;
    const int wave = tid >> 6, lane = tid & 63;
    const bool hi = (lane & 32) != 0;
    const int c31 = lane & 31;
    const int e4 = hi ? 4 : 0;

    const int pid0 = blockIdx.x * 64;
    const int b = pid0 / HW;
    const int p0 = pid0 - b * HW;

    const unsigned* wu = (const unsigned*)wbuf;

    // per-lane A fragments (coalesced uint4 loads)
    H8U aL1, aL2P, aL2S;
    aL1.u4  = ((const uint4*)(wu))[lane];
    aL2P.u4 = ((const uint4*)(wu + 256))[lane];
    aL2S.u4 = ((const uint4*)(wu + 512))[lane];

    // hoisted per-lane tables (loop-invariant)
    float bL1[8];
    #pragma unroll
    for (int e = 0; e < 8; ++e) bL1[e] = wbuf[768 + ((e & 3) + 8 * (e >> 2) + e4)];
    float b1Pl[4], w2Pl[4];
    #pragma unroll
    for (int r = 0; r < 4; ++r) {
        b1Pl[r] = wbuf[784 + r + e4];
        w2Pl[r] = wbuf[792 + r + e4];
    }
    const float bias2P = wbuf[800], bias2S = wbuf[801];

    const f32x16 z16 = {};
    const size_t gstride = (size_t)D * HW;     // x1 channel stride

    unsigned sst[8][4];                        // preS stash (h2 pairs), static idx

    // ---------------- Phase A: L1 (both nets) + P head ----------------
    #pragma unroll
    for (int g8 = 0; g8 < 8; ++g8) {
        const int dt = wave * 4 + (g8 >> 1);
        const int px = (g8 & 1) * 32 + c31;

        // unguarded loads: hi lanes duplicate lo addresses (B hi slots hit
        // aL1's zero K-columns, value irrelevant)
        const float* xp = x1 + ((size_t)b * G * D + dt) * HW + p0 + px;
        float v[8];
        #pragma unroll
        for (int g = 0; g < 8; ++g) v[g] = xp[g * gstride];
        H8U bx;
        #pragma unroll
        for (int j = 0; j < 4; ++j) bx.u[j] = pack2_(v[2 * j], v[2 * j + 1]);

        f32x16 acc = __builtin_amdgcn_mfma_f32_32x32x16_f16(aL1.h, bx.h, z16, 0, 0, 0);

        // l1P (regs 0-7): bias+relu, pack -> L2P B-frag (own regs, no shuffle)
        H8U b2;
        #pragma unroll
        for (int j = 0; j < 4; ++j)
            b2.u[j] = pack2_(fmaxf(acc[2 * j] + bL1[2 * j], 0.0f),
                             fmaxf(acc[2 * j + 1] + bL1[2 * j + 1], 0.0f));
        // preS raw (regs 8-15) -> stash
        #pragma unroll
        for (int j = 0; j < 4; ++j) sst[g8][j] = pack2_(acc[8 + 2 * j], acc[9 + 2 * j]);

        f32x16 acc2 = __builtin_amdgcn_mfma_f32_32x32x16_f16(aL2P.h, b2.h, z16, 0, 0, 0);

        float part = 0.0f;
        #pragma unroll
        for (int r = 0; r < 4; ++r)
            part = fmaf(fmaxf(acc2[r] + b1Pl[r], 0.0f), w2Pl[r], part);
        part += __shfl_xor(part, 32);
        if (!hi) h3buf[dt][px] = part + bias2P;
    }
    __syncthreads();

    // ---------------- vw pass ----------------
    if (tid < 64) {
        float m = h3buf[0][tid];
        #pragma unroll
        for (int k = 1; k < 16; ++k) m = fmaxf(m, h3buf[k][tid]);
        vwbuf[tid] = sigmoidf_(m);
    }
    __syncthreads();

    // ---------------- Phase B: S net ----------------
    H2U b0Sh[4];
    #pragma unroll
    for (int j = 0; j < 4; ++j) {
        const int ee0 = 2 * j, ee1 = 2 * j + 1;
        b0Sh[j].u = pack2_(wbuf[804 + ((ee0 & 3) + 8 * (ee0 >> 2) + e4)],
                           wbuf[804 + ((ee1 & 3) + 8 * (ee1 >> 2) + e4)]);
    }
    float b1Sl[4], w2Sl[4];
    #pragma unroll
    for (int r = 0; r < 4; ++r) {
        b1Sl[r] = wbuf[820 + r + e4];
        w2Sl[r] = wbuf[828 + r + e4];
    }

    #pragma unroll
    for (int g8 = 0; g8 < 8; ++g8) {
        const int dt = wave * 4 + (g8 >> 1);
        const int px = (g8 & 1) * 32 + c31;
        const float vw = vwbuf[px];
        h2v vwh; vwh.x = (_Float16)vw; vwh.y = (_Float16)vw;

        // L2S B-frag: relu(vw*preS + b0S) on own stashed regs (no shuffle)
        H8U b2s;
        #pragma unroll
        for (int j = 0; j < 4; ++j) {
            H2U pv; pv.u = sst[g8][j];
            h2v val = pv.h * vwh + b0Sh[j].h;      // v_pk_fma_f16
            h2v zz = {};
            val = __builtin_elementwise_max(val, zz);
            H2U o2; o2.h = val; b2s.u[j] = o2.u;
        }

        f32x16 acc3 = __builtin_amdgcn_mfma_f32_32x32x16_f16(aL2S.h, b2s.h, z16, 0, 0, 0);

        float part = 0.0f;
        #pragma unroll
        for (int r = 0; r < 4; ++r)
            part = fmaf(fmaxf(acc3[r] + b1Sl[r], 0.0f), w2Sl[r], part);
        part += __shfl_xor(part, 32);
        if (!hi) sbuf[dt][px] = part + bias2S;
    }
    __syncthreads();

    // ---------------- final coalesced write: s, xn ----------------
    {
        const int dt = tid >> 4;
        const int px0 = (tid & 15) * 4;
        const size_t o = ((size_t)(b * D + dt)) * HW + p0 + px0;
        const float4 sv = *(const float4*)&sbuf[dt][px0];
        *(float4*)(s_out + o) = sv;
        const float inv_min = 1.0f / depth_min[b];
        const float inv_max = 1.0f / depth_max[b];
        const float rinv = 1.0f / (inv_min - inv_max);
        const float4 dsv = *(const float4*)(depth_sample + o);
        float4 xv;
        xv.x = (1.0f / dsv.x - inv_max) * rinv;
        xv.y = (1.0f / dsv.y - inv_max) * rinv;
        xv.z = (1.0f / dsv.z - inv_max) * rinv;
        xv.w = (1.0f / dsv.w - inv_max) * rinv;
        *(float4*)(xn_out + o) = xv;
    }
}

// ---------------------------------------------------------------------------
// k_score_depth: 1024 threads = 64 px x 16 depths, one depth/thread.
// Bijective XCD swizzle (nwg = 2560 = 8*320). (unchanged)
// ---------------------------------------------------------------------------
__global__ __launch_bounds__(1024, 8) void k_score_depth(
    const float* __restrict__ s_arr, const float* __restrict__ xn,
    const float* __restrict__ offset, const float* __restrict__ depth_sample,
    float* __restrict__ out)
{
    __shared__ float off_lds[18][64];
    __shared__ float redM[16][64];
    __shared__ float redS[16][64];
    __shared__ float redA[16][64];

    const int bid = blockIdx.x;
    const int wg = (bid & 7) * 320 + (bid >> 3);

    const int tid = threadIdx.x;
    const int pi = tid & 63;
    const int dt = tid >> 6;
    const int pg0_ = wg * 64;
    const int b = pg0_ / HW;
    const int pb0 = pg0_ - b * HW;
    const int p = pb0 + pi;
    const int h = p / W;
    const int w = p - h * W;

    const float* ob = offset + (size_t)b * 18 * HW + pb0;
    for (int idx = tid; idx < 18 * 64; idx += 1024) {
        const int s = idx >> 6, qq = idx & 63;
        off_lds[s][qq] = ob[(size_t)s * HW + qq];
    }
    __syncthreads();

    int a1s[9], a2s[9];
    {
        int ry1[3], ry2[3], cx1[3], cx2[3];
        #pragma unroll
        for (int i = 0; i < 3; ++i) {
            ry1[i] = reflect_(h + (i - 1) * 2, H) * W;
            ry2[i] = reflect_(h + (i - 1) * 4, H) * W;
            cx1[i] = reflect_(w + (i - 1) * 2, W);
            cx2[i] = reflect_(w + (i - 1) * 4, W);
        }
        #pragma unroll
        for (int s = 0; s < 9; ++s) {
            a1s[s] = ry1[s / 3] + cx1[s % 3];
            a2s[s] = ry2[s / 3] + cx2[s % 3];
        }
    }

    const size_t bbase = (size_t)b * D * HW;
    const float* sd = s_arr + bbase + (size_t)dt * HW;
    const float* xd = xn + bbase + (size_t)dt * HW;

    float accs = 0.0f, accx = 0.0f;
    #pragma unroll
    for (int s = 0; s < 9; ++s) {
        const float w1 = off_lds[s + 9][pi];
        const float w2 = off_lds[s][pi];
        accs += 0.5f * (w1 * sd[a1s[s]] + w2 * sd[a2s[s]]);
        accx += 0.5f * (w1 * xd[a1s[s]] + w2 * xd[a2s[s]]);
    }
    const float xc = xd[p];
    const float diff = fminf(fabsf(accx - xc) * 40.0f, 4.0f);
    const float dwv = sigmoidf_((2.0f - diff) * 2.0f);
    const float score = accs * dwv;
    const float dsv = depth_sample[bbase + (size_t)dt * HW + p];

    redM[dt][pi] = score;
    __syncthreads();
    float m = redM[0][pi];
    #pragma unroll
    for (int k = 1; k < 16; ++k) m = fmaxf(m, redM[k][pi]);

    const float e = __expf(score - m);
    redS[dt][pi] = e;
    redA[dt][pi] = dsv * e;
    __syncthreads();

    if (dt == 0) {
        float sum = 0.0f, acc = 0.0f;
        #pragma unroll
        for (int k = 0; k < 16; ++k) { sum += redS[k][pi]; acc += redA[k][pi]; }
        out[pg0_ + pi] = acc / sum;
    }
}

// ---------------------------------------------------------------------------
extern "C" void kernel_launch(void* const* d_in, const int* in_sizes, int n_in,
                              void* d_out, int out_size, void* d_ws, size_t ws_size,
                              hipStream_t stream)
{
    const float* x1           = (const float*)d_in[0];
    const float* offset       = (const float*)d_in[1];
    const float* depth_sample = (const float*)d_in[2];
    const float* depth_min    = (const float*)d_in[3];
    const float* depth_max    = (const float*)d_in[4];
    const float* s_w0 = (const float*)d_in[5];
    const float* s_g0 = (const float*)d_in[6];
    const float* s_b0 = (const float*)d_in[7];
    const float* s_w1 = (const float*)d_in[8];
    const float* s_g1 = (const float*)d_in[9];
    const float* s_b1 = (const float*)d_in[10];
    const float* s_w2 = (const float*)d_in[11];
    const float* s_bias2 = (const float*)d_in[12];
    const float* p_w0 = (const float*)d_in[13];
    const float* p_g0 = (const float*)d_in[14];
    const float* p_b0 = (const float*)d_in[15];
    const float* p_w1 = (const float*)d_in[16];
    const float* p_g1 = (const float*)d_in[17];
    const float* p_b1 = (const float*)d_in[18];
    const float* p_w2 = (const float*)d_in[19];
    const float* p_bias2 = (const float*)d_in[20];

    float* s_arr = (float*)d_ws;                         // B*D*HW
    float* xn    = s_arr + (size_t)B * D * HW;           // B*D*HW
    float* wbuf  = xn + (size_t)B * D * HW;              // WB_TOTAL floats

    k_prep<<<1, 320, 0, stream>>>(
        s_w0, s_g0, s_b0, s_w1, s_g1, s_b1, s_w2, s_bias2,
        p_w0, p_g0, p_b0, p_w1, p_g1, p_b1, p_w2, p_bias2, wbuf);

    k_fused<<<(B * HW) / 64, 256, 0, stream>>>(
        x1, depth_sample, depth_min, depth_max,
        wbuf, s_arr, xn);

    k_score_depth<<<(B * HW) / 64, 1024, 0, stream>>>(
        s_arr, xn, offset, depth_sample, (float*)d_out);
}

// Round 12
// 76.260 us; speedup vs baseline: 1.1028x; 1.1028x over previous
//
#include <hip/hip_runtime.h>
#include <math.h>

// Problem constants (fixed by the reference's setup_inputs)
constexpr int B = 2, G = 8, D = 16, H = 256, W = 320;
constexpr int HW = H * W;
constexpr float EPS = 1e-5f;
constexpr int WSTRIDE = 320;   // floats per folded-weight block (P at 0, S at WSTRIDE)

typedef _Float16 h2 __attribute__((ext_vector_type(2)));

#if __has_builtin(__builtin_amdgcn_fdot2)
#define FDOT2(a, b, c) __builtin_amdgcn_fdot2((a), (b), (c), false)
#else
#define FDOT2(a, b, c) fmaf((float)(a).x, (float)(b).x, fmaf((float)(a).y, (float)(b).y, (c)))
#endif

__device__ __forceinline__ float sigmoidf_(float x) {
    return 1.0f / (1.0f + __expf(-x));
}

__device__ __forceinline__ int reflect_(int i, int n) {
    return i < 0 ? -i : (i >= n ? 2 * n - 2 - i : i);
}

// ---------------------------------------------------------------------------
// k_prep: fold BN into weights and pack as f16 pairs (h2) for v_dot2.
// Layout per net (float-slot stride WSTRIDE):
//   h2 W0h[64]  at slots [0,64)    : 16 outputs x 4 pairs (8 in-ch)
//   h2 W1h[64]  at slots [64,128)  : 8 outputs x 8 pairs (16 in-ch)
//   h2 W2h[4]   at slots [128,132) : 1 output x 4 pairs (8 in-ch)
//   f32 B0[16]  at [132,148), B1[8] at [148,156), bias2 at [156]
// ---------------------------------------------------------------------------
__device__ __forceinline__ void pack_net_(
    const float* __restrict__ w0, const float* __restrict__ g0, const float* __restrict__ b0,
    const float* __restrict__ w1, const float* __restrict__ g1, const float* __restrict__ b1,
    const float* __restrict__ w2, const float* __restrict__ bias2,
    float* __restrict__ o, int t, float rs)
{
    if (t < 64) {
        const int oo = t >> 2, j = t & 3;
        const float s = g0[oo] * rs;
        h2 v; v.x = (_Float16)(w0[oo * 8 + 2 * j] * s);
        v.y = (_Float16)(w0[oo * 8 + 2 * j + 1] * s);
        ((h2*)o)[t] = v;
    } else if (t < 128) {
        const int u = t - 64, oo = u >> 3, j = u & 7;
        const float s = g1[oo] * rs;
        h2 v; v.x = (_Float16)(w1[oo * 16 + 2 * j] * s);
        v.y = (_Float16)(w1[oo * 16 + 2 * j + 1] * s);
        ((h2*)o)[t] = v;
    } else if (t < 132) {
        const int u = t - 128;
        h2 v; v.x = (_Float16)w2[2 * u];
        v.y = (_Float16)w2[2 * u + 1];
        ((h2*)o)[t] = v;
    } else if (t < 148) {
        o[t] = b0[t - 132];
    } else if (t < 156) {
        o[t] = b1[t - 148];
    } else if (t == 156) {
        o[t] = bias2[0];
    }
}

__global__ __launch_bounds__(256) void k_prep(
    const float* __restrict__ sw0, const float* __restrict__ sg0, const float* __restrict__ sb0,
    const float* __restrict__ sw1, const float* __restrict__ sg1, const float* __restrict__ sb1,
    const float* __restrict__ sw2, const float* __restrict__ sbias2,
    const float* __restrict__ pw0, const float* __restrict__ pg0, const float* __restrict__ pb0,
    const float* __restrict__ pw1, const float* __restrict__ pg1, const float* __restrict__ pb1,
    const float* __restrict__ pw2, const float* __restrict__ pbias2,
    float* __restrict__ wbuf)
{
    const int t = threadIdx.x;
    const float rs = rsqrtf(1.0f + EPS);
    pack_net_(pw0, pg0, pb0, pw1, pg1, pb1, pw2, pbias2, wbuf, t, rs);
    pack_net_(sw0, sg0, sb0, sw1, sg1, sb1, sw2, sbias2, wbuf + WSTRIDE, t, rs);
}

// ---------------------------------------------------------------------------
// 1-item MLP via dot2 (round-8 proven)
// ---------------------------------------------------------------------------
__device__ __forceinline__ float mlph_(const float* __restrict__ Wb, const h2 xh[4])
{
    const h2* __restrict__ W0 = (const h2*)Wb;
    const h2* __restrict__ W1 = (const h2*)Wb + 64;
    const h2* __restrict__ W2 = (const h2*)Wb + 128;
    const float* __restrict__ B0 = Wb + 132;
    const float* __restrict__ B1 = Wb + 148;

    float l1[16];
    #pragma unroll
    for (int o = 0; o < 16; ++o) {
        float a = B0[o];
        #pragma unroll
        for (int j = 0; j < 4; ++j) a = FDOT2(W0[o * 4 + j], xh[j], a);
        l1[o] = fmaxf(a, 0.0f);
    }
    h2 l1h[8];
    #pragma unroll
    for (int j = 0; j < 8; ++j) {
        h2 v; v.x = (_Float16)l1[2 * j]; v.y = (_Float16)l1[2 * j + 1];
        l1h[j] = v;
    }
    float l2[8];
    #pragma unroll
    for (int o = 0; o < 8; ++o) {
        float a = B1[o];
        #pragma unroll
        for (int j = 0; j < 8; ++j) a = FDOT2(W1[o * 8 + j], l1h[j], a);
        l2[o] = fmaxf(a, 0.0f);
    }
    h2 l2h[4];
    #pragma unroll
    for (int j = 0; j < 4; ++j) {
        h2 v; v.x = (_Float16)l2[2 * j]; v.y = (_Float16)l2[2 * j + 1];
        l2h[j] = v;
    }
    float h = Wb[156];
    #pragma unroll
    for (int j = 0; j < 4; ++j) h = FDOT2(W2[j], l2h[j], h);
    return h;
}

// ---------------------------------------------------------------------------
// 2-item MLP via dot2: each weight fetch feeds two independent chains.
// ---------------------------------------------------------------------------
__device__ __forceinline__ float2 mlp2d_(const float* __restrict__ Wb,
                                         const h2 xa[4], const h2 xb[4])
{
    const h2* __restrict__ W0 = (const h2*)Wb;
    const h2* __restrict__ W1 = (const h2*)Wb + 64;
    const h2* __restrict__ W2 = (const h2*)Wb + 128;
    const float* __restrict__ B0 = Wb + 132;
    const float* __restrict__ B1 = Wb + 148;

    float l1a[16], l1b[16];
    #pragma unroll
    for (int o = 0; o < 16; ++o) {
        float a = B0[o], c = B0[o];
        #pragma unroll
        for (int j = 0; j < 4; ++j) {
            const h2 w = W0[o * 4 + j];
            a = FDOT2(w, xa[j], a);
            c = FDOT2(w, xb[j], c);
        }
        l1a[o] = fmaxf(a, 0.0f); l1b[o] = fmaxf(c, 0.0f);
    }
    h2 ha_[8], hb_[8];
    #pragma unroll
    for (int j = 0; j < 8; ++j) {
        h2 va; va.x = (_Float16)l1a[2 * j]; va.y = (_Float16)l1a[2 * j + 1]; ha_[j] = va;
        h2 vb; vb.x = (_Float16)l1b[2 * j]; vb.y = (_Float16)l1b[2 * j + 1]; hb_[j] = vb;
    }
    float l2a[8], l2b[8];
    #pragma unroll
    for (int o = 0; o < 8; ++o) {
        float a = B1[o], c = B1[o];
        #pragma unroll
        for (int j = 0; j < 8; ++j) {
            const h2 w = W1[o * 8 + j];
            a = FDOT2(w, ha_[j], a);
            c = FDOT2(w, hb_[j], c);
        }
        l2a[o] = fmaxf(a, 0.0f); l2b[o] = fmaxf(c, 0.0f);
    }
    h2 p2a[4], p2b[4];
    #pragma unroll
    for (int j = 0; j < 4; ++j) {
        h2 va; va.x = (_Float16)l2a[2 * j]; va.y = (_Float16)l2a[2 * j + 1]; p2a[j] = va;
        h2 vb; vb.x = (_Float16)l2b[2 * j]; vb.y = (_Float16)l2b[2 * j + 1]; p2b[j] = vb;
    }
    float hA = Wb[156], hB = Wb[156];
    #pragma unroll
    for (int j = 0; j < 4; ++j) {
        const h2 w = W2[j];
        hA = FDOT2(w, p2a[j], hA);
        hB = FDOT2(w, p2b[j], hB);
    }
    return make_float2(hA, hB);
}

// ---------------------------------------------------------------------------
// Variant A: round-8 kernel, launch_bounds(1024,4) -> VGPR cap 128 (was 64,
// allocator picked 16 -> no ILP). One (pixel,depth) per thread.
// ---------------------------------------------------------------------------
__global__ __launch_bounds__(1024, 4) void k_fusedA(
    const float* __restrict__ x1,
    const float* __restrict__ depth_sample,
    const float* __restrict__ depth_min, const float* __restrict__ depth_max,
    const float* __restrict__ wP, const float* __restrict__ wS,
    float* __restrict__ s_out, float* __restrict__ xn_out, int pbase)
{
    __shared__ float red[16][64];

    const int tid = threadIdx.x;
    const int pi = tid & 63;
    const int dt = tid >> 6;
    const int pid = pbase + blockIdx.x * 64 + pi;
    const int b = pid / HW;
    const int p = pid - b * HW;

    const float* xp = x1 + ((size_t)(b * G * D) + dt) * HW + p;
    float x[8];
    #pragma unroll
    for (int g = 0; g < 8; ++g) x[g] = xp[(size_t)g * D * HW];
    h2 xh[4];
    #pragma unroll
    for (int j = 0; j < 4; ++j) {
        h2 v; v.x = (_Float16)x[2 * j]; v.y = (_Float16)x[2 * j + 1];
        xh[j] = v;
    }

    red[dt][pi] = mlph_(wP, xh);
    __syncthreads();

    float mx = red[0][pi];
    #pragma unroll
    for (int k = 1; k < 16; ++k) mx = fmaxf(mx, red[k][pi]);
    const float vw = sigmoidf_(mx);

    h2 vwh; vwh.x = (_Float16)vw; vwh.y = (_Float16)vw;
    h2 xsh[4];
    #pragma unroll
    for (int j = 0; j < 4; ++j) xsh[j] = xh[j] * vwh;
    const float hS = mlph_(wS, xsh);

    const size_t oidx = (size_t)(b * D + dt) * HW + p;
    s_out[oidx] = hS;

    const float inv_min = 1.0f / depth_min[b];
    const float inv_max = 1.0f / depth_max[b];
    const float rinv = 1.0f / (inv_min - inv_max);
    const float ds = depth_sample[oidx];
    xn_out[oidx] = (1.0f / ds - inv_max) * rinv;
}

// ---------------------------------------------------------------------------
// Variant B: 2 pixels/thread, 512 threads = 32 pairs x 16 depths,
// launch_bounds(512,4) -> VGPR cap 128. ILP from two independent chains.
// ---------------------------------------------------------------------------
__global__ __launch_bounds__(512, 4) void k_fusedB(
    const float* __restrict__ x1,
    const float* __restrict__ depth_sample,
    const float* __restrict__ depth_min, const float* __restrict__ depth_max,
    const float* __restrict__ wP, const float* __restrict__ wS,
    float* __restrict__ s_out, float* __restrict__ xn_out, int pbase)
{
    __shared__ float2 red[16][32];

    const int tid = threadIdx.x;
    const int pl = tid & 31;           // pixel-pair lane
    const int dt = tid >> 5;           // depth 0..15
    const int pid0 = pbase + blockIdx.x * 64 + 2 * pl;
    const int b = pid0 / HW;
    const int p0 = pid0 - b * HW;

    const float* xp = x1 + ((size_t)(b * G * D) + dt) * HW + p0;
    h2 xa[4], xb[4];
    {
        float2 xv[8];
        #pragma unroll
        for (int g = 0; g < 8; ++g)
            xv[g] = *reinterpret_cast<const float2*>(xp + (size_t)g * D * HW);
        #pragma unroll
        for (int j = 0; j < 4; ++j) {
            h2 va; va.x = (_Float16)xv[2 * j].x; va.y = (_Float16)xv[2 * j + 1].x; xa[j] = va;
            h2 vb; vb.x = (_Float16)xv[2 * j].y; vb.y = (_Float16)xv[2 * j + 1].y; xb[j] = vb;
        }
    }

    red[dt][pl] = mlp2d_(wP, xa, xb);
    __syncthreads();

    float2 mx = red[0][pl];
    #pragma unroll
    for (int k = 1; k < 16; ++k) {
        const float2 r = red[k][pl];
        mx.x = fmaxf(mx.x, r.x); mx.y = fmaxf(mx.y, r.y);
    }
    const float vwa = sigmoidf_(mx.x);
    const float vwb = sigmoidf_(mx.y);

    h2 va; va.x = (_Float16)vwa; va.y = (_Float16)vwa;
    h2 vb; vb.x = (_Float16)vwb; vb.y = (_Float16)vwb;
    h2 xsa[4], xsb[4];
    #pragma unroll
    for (int j = 0; j < 4; ++j) { xsa[j] = xa[j] * va; xsb[j] = xb[j] * vb; }
    const float2 hS = mlp2d_(wS, xsa, xsb);

    const size_t oidx = (size_t)(b * D + dt) * HW + p0;
    *reinterpret_cast<float2*>(s_out + oidx) = hS;

    const float inv_min = 1.0f / depth_min[b];
    const float inv_max = 1.0f / depth_max[b];
    const float rinv = 1.0f / (inv_min - inv_max);
    const float2 ds = *reinterpret_cast<const float2*>(depth_sample + oidx);
    *reinterpret_cast<float2*>(xn_out + oidx) =
        make_float2((1.0f / ds.x - inv_max) * rinv,
                    (1.0f / ds.y - inv_max) * rinv);
}

// ---------------------------------------------------------------------------
// k_score_depth: 1024 threads = 64 px x 16 depths, one depth/thread.
// Bijective XCD swizzle (nwg = 2560 = 8*320). (unchanged, ~20 us)
// ---------------------------------------------------------------------------
__global__ __launch_bounds__(1024, 8) void k_score_depth(
    const float* __restrict__ s_arr, const float* __restrict__ xn,
    const float* __restrict__ offset, const float* __restrict__ depth_sample,
    float* __restrict__ out)
{
    __shared__ float off_lds[18][64];
    __shared__ float redM[16][64];
    __shared__ float redS[16][64];
    __shared__ float redA[16][64];

    const int bid = blockIdx.x;
    const int wg = (bid & 7) * 320 + (bid >> 3);

    const int tid = threadIdx.x;
    const int pi = tid & 63;
    const int dt = tid >> 6;
    const int pg0_ = wg * 64;
    const int b = pg0_ / HW;
    const int pb0 = pg0_ - b * HW;
    const int p = pb0 + pi;
    const int h = p / W;
    const int w = p - h * W;

    const float* ob = offset + (size_t)b * 18 * HW + pb0;
    for (int idx = tid; idx < 18 * 64; idx += 1024) {
        const int s = idx >> 6, qq = idx & 63;
        off_lds[s][qq] = ob[(size_t)s * HW + qq];
    }
    __syncthreads();

    int a1s[9], a2s[9];
    {
        int ry1[3], ry2[3], cx1[3], cx2[3];
        #pragma unroll
        for (int i = 0; i < 3; ++i) {
            ry1[i] = reflect_(h + (i - 1) * 2, H) * W;
            ry2[i] = reflect_(h + (i - 1) * 4, H) * W;
            cx1[i] = reflect_(w + (i - 1) * 2, W);
            cx2[i] = reflect_(w + (i - 1) * 4, W);
        }
        #pragma unroll
        for (int s = 0; s < 9; ++s) {
            a1s[s] = ry1[s / 3] + cx1[s % 3];
            a2s[s] = ry2[s / 3] + cx2[s % 3];
        }
    }

    const size_t bbase = (size_t)b * D * HW;
    const float* sd = s_arr + bbase + (size_t)dt * HW;
    const float* xd = xn + bbase + (size_t)dt * HW;

    float accs = 0.0f, accx = 0.0f;
    #pragma unroll
    for (int s = 0; s < 9; ++s) {
        const float w1 = off_lds[s + 9][pi];
        const float w2 = off_lds[s][pi];
        accs += 0.5f * (w1 * sd[a1s[s]] + w2 * sd[a2s[s]]);
        accx += 0.5f * (w1 * xd[a1s[s]] + w2 * xd[a2s[s]]);
    }
    const float xc = xd[p];
    const float diff = fminf(fabsf(accx - xc) * 40.0f, 4.0f);
    const float dwv = sigmoidf_((2.0f - diff) * 2.0f);
    const float score = accs * dwv;
    const float dsv = depth_sample[bbase + (size_t)dt * HW + p];

    redM[dt][pi] = score;
    __syncthreads();
    float m = redM[0][pi];
    #pragma unroll
    for (int k = 1; k < 16; ++k) m = fmaxf(m, redM[k][pi]);

    const float e = __expf(score - m);
    redS[dt][pi] = e;
    redA[dt][pi] = dsv * e;
    __syncthreads();

    if (dt == 0) {
        float sum = 0.0f, acc = 0.0f;
        #pragma unroll
        for (int k = 0; k < 16; ++k) { sum += redS[k][pi]; acc += redA[k][pi]; }
        out[pg0_ + pi] = acc / sum;
    }
}

// ---------------------------------------------------------------------------
extern "C" void kernel_launch(void* const* d_in, const int* in_sizes, int n_in,
                              void* d_out, int out_size, void* d_ws, size_t ws_size,
                              hipStream_t stream)
{
    const float* x1           = (const float*)d_in[0];
    const float* offset       = (const float*)d_in[1];
    const float* depth_sample = (const float*)d_in[2];
    const float* depth_min    = (const float*)d_in[3];
    const float* depth_max    = (const float*)d_in[4];
    const float* s_w0 = (const float*)d_in[5];
    const float* s_g0 = (const float*)d_in[6];
    const float* s_b0 = (const float*)d_in[7];
    const float* s_w1 = (const float*)d_in[8];
    const float* s_g1 = (const float*)d_in[9];
    const float* s_b1 = (const float*)d_in[10];
    const float* s_w2 = (const float*)d_in[11];
    const float* s_bias2 = (const float*)d_in[12];
    const float* p_w0 = (const float*)d_in[13];
    const float* p_g0 = (const float*)d_in[14];
    const float* p_b0 = (const float*)d_in[15];
    const float* p_w1 = (const float*)d_in[16];
    const float* p_g1 = (const float*)d_in[17];
    const float* p_b1 = (const float*)d_in[18];
    const float* p_w2 = (const float*)d_in[19];
    const float* p_bias2 = (const float*)d_in[20];

    float* s_arr = (float*)d_ws;                         // B*D*HW
    float* xn    = s_arr + (size_t)B * D * HW;           // B*D*HW
    float* wbuf  = xn + (size_t)B * D * HW;              // 2*WSTRIDE floats

    k_prep<<<1, 256, 0, stream>>>(
        s_w0, s_g0, s_b0, s_w1, s_g1, s_b1, s_w2, s_bias2,
        p_w0, p_g0, p_b0, p_w1, p_g1, p_b1, p_w2, p_bias2, wbuf);

    const int half = HW;   // batch 0 -> variant A, batch 1 -> variant B

    k_fusedA<<<half / 64, 1024, 0, stream>>>(
        x1, depth_sample, depth_min, depth_max,
        wbuf, wbuf + WSTRIDE, s_arr, xn, 0);

    k_fusedB<<<half / 64, 512, 0, stream>>>(
        x1, depth_sample, depth_min, depth_max,
        wbuf, wbuf + WSTRIDE, s_arr, xn, half);

    k_score_depth<<<(B * HW) / 64, 1024, 0, stream>>>(
        s_arr, xn, offset, depth_sample, (float*)d_out);
}

// Round 13
// 74.128 us; speedup vs baseline: 1.1346x; 1.0288x over previous
//
#include <hip/hip_runtime.h>
#include <math.h>

// Problem constants (fixed by the reference's setup_inputs)
constexpr int B = 2, G = 8, D = 16, H = 256, W = 320;
constexpr int HW = H * W;
constexpr float EPS = 1e-5f;

typedef _Float16 half8  __attribute__((ext_vector_type(8)));
typedef _Float16 h2v    __attribute__((ext_vector_type(2)));
typedef float    f32x16 __attribute__((ext_vector_type(16)));

union H8U { half8 h; unsigned u[4]; uint4 u4; };
union H2U { h2v h; unsigned u; };

// wbuf layout:
//   u32  [0..256)    aL1  : 64 lanes x 4 dwords (L1 A-frag, P rows 0-15, S rows 16-31, K>=8 zero)
//   u32  [256..512)  aL2P : 64 lanes x 4 dwords (W1P, K-PERMUTED to C-layout order)
//   u32  [512..768)  aL2S : 64 lanes x 4 dwords (W1S, K-permuted)
//   f32  [768..784)  b0P[16]; [784..792) b1P[8]; [792..800) w2P[8]
//   f32  [800] bias2P; [801] bias2S
//   f32  [804..820)  b0S[16]; [820..828) b1S[8]; [828..836) w2S[8]
constexpr int WB_TOTAL = 840;

__device__ __forceinline__ float sigmoidf_(float x) {
    return 1.0f / (1.0f + __expf(-x));
}
__device__ __forceinline__ int reflect_(int i, int n) {
    return i < 0 ? -i : (i >= n ? 2 * n - 2 - i : i);
}
__device__ __forceinline__ unsigned pack2_(float a, float b) {
    H2U p; p.h.x = (_Float16)a; p.h.y = (_Float16)b; return p.u;
}

// ---------------------------------------------------------------------------
// k_prep: MFMA-ready fragments (BN folded) + bias tables. (proven round 10)
// A-frag (32x32x16): lane l holds A[row=l&31][k=(l>>5)*8+e], e=0..7.
// aL2*: K-permuted so slot k=(l>>5)*8+e maps to l1-row (e&3)+8*(e>>2)+((l>>5)?4:0)
// -> L2 B-fragment = pack of the lane's own acc regs (no cross-lane traffic).
// ---------------------------------------------------------------------------
__global__ __launch_bounds__(320) void k_prep(
    const float* __restrict__ sw0, const float* __restrict__ sg0, const float* __restrict__ sb0,
    const float* __restrict__ sw1, const float* __restrict__ sg1, const float* __restrict__ sb1,
    const float* __restrict__ sw2, const float* __restrict__ sbias2,
    const float* __restrict__ pw0, const float* __restrict__ pg0, const float* __restrict__ pb0,
    const float* __restrict__ pw1, const float* __restrict__ pg1, const float* __restrict__ pb1,
    const float* __restrict__ pw2, const float* __restrict__ pbias2,
    float* __restrict__ wbuf)
{
    const int t = threadIdx.x;
    const float rs = rsqrtf(1.0f + EPS);
    unsigned* wu = (unsigned*)wbuf;

    if (t < 64) {
        unsigned dw[4] = {0u, 0u, 0u, 0u};
        if (t < 32) {
            const int row = t;
            #pragma unroll
            for (int j = 0; j < 4; ++j) {
                float a0, a1;
                if (row < 16) {
                    const float s = pg0[row] * rs;
                    a0 = pw0[row * 8 + 2 * j] * s; a1 = pw0[row * 8 + 2 * j + 1] * s;
                } else {
                    const float s = sg0[row - 16] * rs;
                    a0 = sw0[(row - 16) * 8 + 2 * j] * s; a1 = sw0[(row - 16) * 8 + 2 * j + 1] * s;
                }
                dw[j] = pack2_(a0, a1);
            }
        }
        #pragma unroll
        for (int j = 0; j < 4; ++j) wu[t * 4 + j] = dw[j];
    } else if (t < 128) {
        const int l = t - 64, row = l & 31;
        const int e4 = (l >> 5) ? 4 : 0;
        unsigned dw[4] = {0u, 0u, 0u, 0u};
        if (row < 8) {
            const float s = pg1[row] * rs;
            #pragma unroll
            for (int j = 0; j < 4; ++j) {
                const int e0 = 2 * j, e1 = 2 * j + 1;
                const int k0 = (e0 & 3) + 8 * (e0 >> 2) + e4;
                const int k1 = (e1 & 3) + 8 * (e1 >> 2) + e4;
                dw[j] = pack2_(pw1[row * 16 + k0] * s, pw1[row * 16 + k1] * s);
            }
        }
        #pragma unroll
        for (int j = 0; j < 4; ++j) wu[256 + l * 4 + j] = dw[j];
    } else if (t < 192) {
        const int l = t - 128, row = l & 31;
        const int e4 = (l >> 5) ? 4 : 0;
        unsigned dw[4] = {0u, 0u, 0u, 0u};
        if (row < 8) {
            const float s = sg1[row] * rs;
            #pragma unroll
            for (int j = 0; j < 4; ++j) {
                const int e0 = 2 * j, e1 = 2 * j + 1;
                const int k0 = (e0 & 3) + 8 * (e0 >> 2) + e4;
                const int k1 = (e1 & 3) + 8 * (e1 >> 2) + e4;
                dw[j] = pack2_(sw1[row * 16 + k0] * s, sw1[row * 16 + k1] * s);
            }
        }
        #pragma unroll
        for (int j = 0; j < 4; ++j) wu[512 + l * 4 + j] = dw[j];
    } else {
        const int u = t - 192;
        if (u < 16)       wbuf[768 + u] = pb0[u];
        else if (u < 24)  wbuf[784 + (u - 16)] = pb1[u - 16];
        else if (u < 32)  wbuf[792 + (u - 24)] = pw2[u - 24];
        else if (u == 32) wbuf[800] = pbias2[0];
        else if (u == 33) wbuf[801] = sbias2[0];
        else if (u < 50)  wbuf[804 + (u - 34)] = sb0[u - 34];
        else if (u < 58)  wbuf[820 + (u - 50)] = sb1[u - 50];
        else if (u < 66)  wbuf[828 + (u - 58)] = sw2[u - 58];
    }
}

// ---------------------------------------------------------------------------
// k_fused (MFMA, shuffle-free): block = 256 thr (4 waves) = 64 px x 16 dt.
// IDENTICAL math to round 10 (HW-verified absmax 4.0). Changes:
//   * __launch_bounds__(256) only -- VGPR free to grow; (256,4)'s 64-cap
//     caused the 112 MB scratch-spill storm (WRITE_SIZE evidence).
//   * aL2S fragment loaded in phase B (shrinks phase-A live set).
// ---------------------------------------------------------------------------
__global__ __launch_bounds__(256) void k_fused(
    const float* __restrict__ x1,
    const float* __restrict__ depth_sample,
    const float* __restrict__ depth_min, const float* __restrict__ depth_max,
    const float* __restrict__ wbuf,
    float* __restrict__ s_out, float* __restrict__ xn_out)
{
    __shared__ float h3buf[16][64];
    __shared__ float vwbuf[64];
    __shared__ float sbuf[16][64];

    const int tid = threadIdx.x;
    const int wave = tid >> 6, lane = tid & 63;
    const bool hi = (lane & 32) != 0;
    const int c31 = lane & 31;
    const int e4 = hi ? 4 : 0;

    const int pid0 = blockIdx.x * 64;
    const int b = pid0 / HW;
    const int p0 = pid0 - b * HW;

    const unsigned* wu = (const unsigned*)wbuf;

    // per-lane A fragments (phase-A set only)
    H8U aL1, aL2P;
    aL1.u4  = ((const uint4*)(wu))[lane];
    aL2P.u4 = ((const uint4*)(wu + 256))[lane];

    // hoisted per-lane tables (loop-invariant)
    float bL1[8];
    #pragma unroll
    for (int e = 0; e < 8; ++e) bL1[e] = wbuf[768 + ((e & 3) + 8 * (e >> 2) + e4)];
    float b1Pl[4], w2Pl[4];
    #pragma unroll
    for (int r = 0; r < 4; ++r) {
        b1Pl[r] = wbuf[784 + r + e4];
        w2Pl[r] = wbuf[792 + r + e4];
    }
    const float bias2P = wbuf[800], bias2S = wbuf[801];

    const f32x16 z16 = {};
    const size_t gstride = (size_t)D * HW;     // x1 channel stride

    unsigned sst[8][4];                        // preS stash (h2 pairs), static idx

    // ---------------- Phase A: L1 (both nets) + P head ----------------
    #pragma unroll
    for (int g8 = 0; g8 < 8; ++g8) {
        const int dt = wave * 4 + (g8 >> 1);
        const int px = (g8 & 1) * 32 + c31;

        // unguarded loads: hi lanes duplicate lo addresses (their B slots hit
        // aL1's zero K-columns, value irrelevant; same cache lines)
        const float* xp = x1 + ((size_t)b * G * D + dt) * HW + p0 + px;
        float v[8];
        #pragma unroll
        for (int g = 0; g < 8; ++g) v[g] = xp[g * gstride];
        H8U bx;
        #pragma unroll
        for (int j = 0; j < 4; ++j) bx.u[j] = pack2_(v[2 * j], v[2 * j + 1]);

        f32x16 acc = __builtin_amdgcn_mfma_f32_32x32x16_f16(aL1.h, bx.h, z16, 0, 0, 0);

        // l1P (regs 0-7): bias+relu, pack -> L2P B-frag (own regs, no shuffle)
        H8U b2;
        #pragma unroll
        for (int j = 0; j < 4; ++j)
            b2.u[j] = pack2_(fmaxf(acc[2 * j] + bL1[2 * j], 0.0f),
                             fmaxf(acc[2 * j + 1] + bL1[2 * j + 1], 0.0f));
        // preS raw (regs 8-15) -> stash
        #pragma unroll
        for (int j = 0; j < 4; ++j) sst[g8][j] = pack2_(acc[8 + 2 * j], acc[9 + 2 * j]);

        f32x16 acc2 = __builtin_amdgcn_mfma_f32_32x32x16_f16(aL2P.h, b2.h, z16, 0, 0, 0);

        float part = 0.0f;
        #pragma unroll
        for (int r = 0; r < 4; ++r)
            part = fmaf(fmaxf(acc2[r] + b1Pl[r], 0.0f), w2Pl[r], part);
        part += __shfl_xor(part, 32);
        if (!hi) h3buf[dt][px] = part + bias2P;
    }
    __syncthreads();

    // ---------------- vw pass ----------------
    if (tid < 64) {
        float m = h3buf[0][tid];
        #pragma unroll
        for (int k = 1; k < 16; ++k) m = fmaxf(m, h3buf[k][tid]);
        vwbuf[tid] = sigmoidf_(m);
    }
    __syncthreads();

    // ---------------- Phase B: S net ----------------
    H8U aL2S;
    aL2S.u4 = ((const uint4*)(wu + 512))[lane];

    H2U b0Sh[4];
    #pragma unroll
    for (int j = 0; j < 4; ++j) {
        const int ee0 = 2 * j, ee1 = 2 * j + 1;
        b0Sh[j].u = pack2_(wbuf[804 + ((ee0 & 3) + 8 * (ee0 >> 2) + e4)],
                           wbuf[804 + ((ee1 & 3) + 8 * (ee1 >> 2) + e4)]);
    }
    float b1Sl[4], w2Sl[4];
    #pragma unroll
    for (int r = 0; r < 4; ++r) {
        b1Sl[r] = wbuf[820 + r + e4];
        w2Sl[r] = wbuf[828 + r + e4];
    }

    #pragma unroll
    for (int g8 = 0; g8 < 8; ++g8) {
        const int dt = wave * 4 + (g8 >> 1);
        const int px = (g8 & 1) * 32 + c31;
        const float vw = vwbuf[px];
        h2v vwh; vwh.x = (_Float16)vw; vwh.y = (_Float16)vw;

        // L2S B-frag: relu(vw*preS + b0S) on own stashed regs (no shuffle)
        H8U b2s;
        #pragma unroll
        for (int j = 0; j < 4; ++j) {
            H2U pv; pv.u = sst[g8][j];
            h2v val = pv.h * vwh + b0Sh[j].h;      // v_pk_fma_f16
            h2v zz = {};
            val = __builtin_elementwise_max(val, zz);
            H2U o2; o2.h = val; b2s.u[j] = o2.u;
        }

        f32x16 acc3 = __builtin_amdgcn_mfma_f32_32x32x16_f16(aL2S.h, b2s.h, z16, 0, 0, 0);

        float part = 0.0f;
        #pragma unroll
        for (int r = 0; r < 4; ++r)
            part = fmaf(fmaxf(acc3[r] + b1Sl[r], 0.0f), w2Sl[r], part);
        part += __shfl_xor(part, 32);
        if (!hi) sbuf[dt][px] = part + bias2S;
    }
    __syncthreads();

    // ---------------- final coalesced write: s, xn ----------------
    {
        const int dt = tid >> 4;
        const int px0 = (tid & 15) * 4;
        const size_t o = ((size_t)(b * D + dt)) * HW + p0 + px0;
        const float4 sv = *(const float4*)&sbuf[dt][px0];
        *(float4*)(s_out + o) = sv;
        const float inv_min = 1.0f / depth_min[b];
        const float inv_max = 1.0f / depth_max[b];
        const float rinv = 1.0f / (inv_min - inv_max);
        const float4 dsv = *(const float4*)(depth_sample + o);
        float4 xv;
        xv.x = (1.0f / dsv.x - inv_max) * rinv;
        xv.y = (1.0f / dsv.y - inv_max) * rinv;
        xv.z = (1.0f / dsv.z - inv_max) * rinv;
        xv.w = (1.0f / dsv.w - inv_max) * rinv;
        *(float4*)(xn_out + o) = xv;
    }
}

// ---------------------------------------------------------------------------
// k_score_depth: 1024 threads = 64 px x 16 depths, one depth/thread.
// Bijective XCD swizzle (nwg = 2560 = 8*320). (unchanged, ~20 us)
// ---------------------------------------------------------------------------
__global__ __launch_bounds__(1024, 8) void k_score_depth(
    const float* __restrict__ s_arr, const float* __restrict__ xn,
    const float* __restrict__ offset, const float* __restrict__ depth_sample,
    float* __restrict__ out)
{
    __shared__ float off_lds[18][64];
    __shared__ float redM[16][64];
    __shared__ float redS[16][64];
    __shared__ float redA[16][64];

    const int bid = blockIdx.x;
    const int wg = (bid & 7) * 320 + (bid >> 3);

    const int tid = threadIdx.x;
    const int pi = tid & 63;
    const int dt = tid >> 6;
    const int pg0_ = wg * 64;
    const int b = pg0_ / HW;
    const int pb0 = pg0_ - b * HW;
    const int p = pb0 + pi;
    const int h = p / W;
    const int w = p - h * W;

    const float* ob = offset + (size_t)b * 18 * HW + pb0;
    for (int idx = tid; idx < 18 * 64; idx += 1024) {
        const int s = idx >> 6, qq = idx & 63;
        off_lds[s][qq] = ob[(size_t)s * HW + qq];
    }
    __syncthreads();

    int a1s[9], a2s[9];
    {
        int ry1[3], ry2[3], cx1[3], cx2[3];
        #pragma unroll
        for (int i = 0; i < 3; ++i) {
            ry1[i] = reflect_(h + (i - 1) * 2, H) * W;
            ry2[i] = reflect_(h + (i - 1) * 4, H) * W;
            cx1[i] = reflect_(w + (i - 1) * 2, W);
            cx2[i] = reflect_(w + (i - 1) * 4, W);
        }
        #pragma unroll
        for (int s = 0; s < 9; ++s) {
            a1s[s] = ry1[s / 3] + cx1[s % 3];
            a2s[s] = ry2[s / 3] + cx2[s % 3];
        }
    }

    const size_t bbase = (size_t)b * D * HW;
    const float* sd = s_arr + bbase + (size_t)dt * HW;
    const float* xd = xn + bbase + (size_t)dt * HW;

    float accs = 0.0f, accx = 0.0f;
    #pragma unroll
    for (int s = 0; s < 9; ++s) {
        const float w1 = off_lds[s + 9][pi];
        const float w2 = off_lds[s][pi];
        accs += 0.5f * (w1 * sd[a1s[s]] + w2 * sd[a2s[s]]);
        accx += 0.5f * (w1 * xd[a1s[s]] + w2 * xd[a2s[s]]);
    }
    const float xc = xd[p];
    const float diff = fminf(fabsf(accx - xc) * 40.0f, 4.0f);
    const float dwv = sigmoidf_((2.0f - diff) * 2.0f);
    const float score = accs * dwv;
    const float dsv = depth_sample[bbase + (size_t)dt * HW + p];

    redM[dt][pi] = score;
    __syncthreads();
    float m = redM[0][pi];
    #pragma unroll
    for (int k = 1; k < 16; ++k) m = fmaxf(m, redM[k][pi]);

    const float e = __expf(score - m);
    redS[dt][pi] = e;
    redA[dt][pi] = dsv * e;
    __syncthreads();

    if (dt == 0) {
        float sum = 0.0f, acc = 0.0f;
        #pragma unroll
        for (int k = 0; k < 16; ++k) { sum += redS[k][pi]; acc += redA[k][pi]; }
        out[pg0_ + pi] = acc / sum;
    }
}

// ---------------------------------------------------------------------------
extern "C" void kernel_launch(void* const* d_in, const int* in_sizes, int n_in,
                              void* d_out, int out_size, void* d_ws, size_t ws_size,
                              hipStream_t stream)
{
    const float* x1           = (const float*)d_in[0];
    const float* offset       = (const float*)d_in[1];
    const float* depth_sample = (const float*)d_in[2];
    const float* depth_min    = (const float*)d_in[3];
    const float* depth_max    = (const float*)d_in[4];
    const float* s_w0 = (const float*)d_in[5];
    const float* s_g0 = (const float*)d_in[6];
    const float* s_b0 = (const float*)d_in[7];
    const float* s_w1 = (const float*)d_in[8];
    const float* s_g1 = (const float*)d_in[9];
    const float* s_b1 = (const float*)d_in[10];
    const float* s_w2 = (const float*)d_in[11];
    const float* s_bias2 = (const float*)d_in[12];
    const float* p_w0 = (const float*)d_in[13];
    const float* p_g0 = (const float*)d_in[14];
    const float* p_b0 = (const float*)d_in[15];
    const float* p_w1 = (const float*)d_in[16];
    const float* p_g1 = (const float*)d_in[17];
    const float* p_b1 = (const float*)d_in[18];
    const float* p_w2 = (const float*)d_in[19];
    const float* p_bias2 = (const float*)d_in[20];

    float* s_arr = (float*)d_ws;                         // B*D*HW
    float* xn    = s_arr + (size_t)B * D * HW;           // B*D*HW
    float* wbuf  = xn + (size_t)B * D * HW;              // WB_TOTAL floats

    k_prep<<<1, 320, 0, stream>>>(
        s_w0, s_g0, s_b0, s_w1, s_g1, s_b1, s_w2, s_bias2,
        p_w0, p_g0, p_b0, p_w1, p_g1, p_b1, p_w2, p_bias2, wbuf);

    k_fused<<<(B * HW) / 64, 256, 0, stream>>>(
        x1, depth_sample, depth_min, depth_max,
        wbuf, s_arr, xn);

    k_score_depth<<<(B * HW) / 64, 1024, 0, stream>>>(
        s_arr, xn, offset, depth_sample, (float*)d_out);
}